// Round 1
// 422.620 us; speedup vs baseline: 1.7465x; 1.7465x over previous
//
#include <hip/hip_runtime.h>

#define B_     256
#define L_     128
#define D_     6
#define F_     200
#define FA_    39
#define FB_    10
#define PAD_   127       // L-1 padding atom index
#define LMASK  127
#define NT     256
#define KC     (F_/4)    // 50 float4 chunks per F-row
#define NTILE  16
#define NQ     (NTILE * D_)   // 96 pairs
#define NF     (B_ * L_ * F_) // 6,553,600 floats
#define MSZ    (F_ * F_)      // 40,000 floats per matrix
#define NNODES (B_ * L_)      // 32768
#define KP     224            // K padded to 7*32 (MFMA reads k < 224)
#define KPP    232            // LDS row stride: 464B -> bank step 20 (conflict-free)
#define KSTEPS 7
#define NTL    13             // N tiles of 16 (200 -> 208)
#define FRAG_TOTAL (14 * NTL * KSTEPS * 64)

typedef __attribute__((ext_vector_type(8))) short sh8;
typedef __attribute__((ext_vector_type(4))) float f32x4;

__device__ __forceinline__ float lrelu(float x) { return x >= 0.0f ? x : 0.01f * x; }
__device__ __forceinline__ float sigm(float x)  { return 1.0f / (1.0f + __expf(-x)); }
__device__ __forceinline__ unsigned short f2b(float x) {   // fp32 -> bf16 RNE
    unsigned int u = __float_as_uint(x);
    unsigned int r = (u + 0x7FFFu + ((u >> 16) & 1u)) >> 16;
    return (unsigned short)r;
}
__device__ __forceinline__ uint2 pack4(float4 v) {
    uint2 p;
    p.x = (unsigned int)f2b(v.x) | ((unsigned int)f2b(v.y) << 16);
    p.y = (unsigned int)f2b(v.z) | ((unsigned int)f2b(v.w) << 16);
    return p;
}
// A-fragment from LDS bf16 [NTILE][KPP]: A[m=lane&15][k=ks*32+quad*8+j]
#define AFRAG(arr, ks) (*(const sh8*)&arr[lane & 15][(ks) * 32 + ((lane >> 4) << 3)])
__device__ __forceinline__ sh8 bfrag(const unsigned short* __restrict__ WFr,
                                     int mat, int t, int ks, int lane) {
    return *(const sh8*)(WFr + ((((size_t)mat * NTL + t) * KSTEPS + ks) * 64 + lane) * 8);
}

// ============== prep: cur0 = lrelu(atom emb), PA/PB partial nbr emb ==============
// Weight-stationary restructure: lane owns output column f, weights live in
// registers (loaded once per block via coalesced LDS bounce; stride-39/49 LDS
// reads are 2-way bank aliases = free). Node inputs are wave-UNIFORM scalar
// loads (s_load path) instead of the old 64-distinct-lines-per-wave scatter
// that made this kernel transaction-bound (405us @ VALUBusy 6%).
#define PN2 64
__global__ __launch_bounds__(NT)
void prep_kernel(const float* __restrict__ atom_list, const float* __restrict__ bond_list,
                 const float* __restrict__ atom_W, const float* __restrict__ atom_b,
                 const float* __restrict__ nbr_W,
                 float* __restrict__ cur0, float* __restrict__ PA, float* __restrict__ PB)
{
    const int node0 = blockIdx.x * PN2;
    const int tid   = threadIdx.x;
    const int f     = tid;
    const bool valid = (f < F_);
    const int fc    = valid ? f : 0;

    __shared__ float wsh[F_ * (FA_ + FB_)];   // 9800 floats = 39.2 KB

    float wa[FA_];
    float wn[FA_ + FB_];

    // stage atom_W coalesced -> per-lane row into registers
    for (int i = tid; i < F_ * FA_; i += NT) wsh[i] = atom_W[i];
    __syncthreads();
    #pragma unroll
    for (int k = 0; k < FA_; ++k) wa[k] = wsh[fc * FA_ + k];
    __syncthreads();
    // stage nbr_W coalesced -> per-lane row into registers
    for (int i = tid; i < F_ * (FA_ + FB_); i += NT) wsh[i] = nbr_W[i];
    __syncthreads();
    #pragma unroll
    for (int k = 0; k < FA_ + FB_; ++k) wn[k] = wsh[fc * (FA_ + FB_) + k];

    const float ab = atom_b[fc];

    for (int n = 0; n < PN2; ++n) {
        const float* __restrict__ ar = atom_list + (size_t)(node0 + n) * FA_;
        const float* __restrict__ br = bond_list + (size_t)(node0 + n) * FB_;
        float accA = ab, accPA = 0.0f, accPB = 0.0f;
        #pragma unroll
        for (int k = 0; k < FA_; ++k) {
            const float a = ar[k];          // wave-uniform -> scalar load
            accA  += a * wa[k];
            accPA += a * wn[k];
        }
        #pragma unroll
        for (int k = 0; k < FB_; ++k) accPB += br[k] * wn[FA_ + k];
        if (valid) {
            const size_t o = (size_t)(node0 + n) * F_ + f;
            cur0[o] = lrelu(accA);
            PA[o]   = accPA;
            PB[o]   = accPB;
        }
    }
}

// ===== build bf16 B-fragments for 14 F×F matrices (zero-padded to 208×224) =====
__global__ void build_frags(const float* __restrict__ attend_W,
                            const float* __restrict__ gru_Wih,
                            const float* __restrict__ gru_Whh,
                            unsigned short* __restrict__ WF)
{
    const int i = blockIdx.x * blockDim.x + threadIdx.x;
    if (i >= FRAG_TOTAL) return;
    const int lane = i & 63;
    int rest = i >> 6;
    const int ks = rest % KSTEPS; rest /= KSTEPS;
    const int t  = rest % NTL;
    const int m  = rest / NTL;
    const int n  = t * 16 + (lane & 15);
    const int k0 = ks * 32 + ((lane >> 4) << 3);
    const int r = m / 7, tt = m - r * 7;
    const float* src;
    if (tt == 0)      src = attend_W + (size_t)r * MSZ;
    else if (tt <= 3) src = gru_Wih + ((size_t)r * 3 + (tt - 1)) * MSZ;
    else              src = gru_Whh + ((size_t)r * 3 + (tt - 4)) * MSZ;
    unsigned short o[8];
    #pragma unroll
    for (int j = 0; j < 8; ++j) {
        const int k = k0 + j;
        const float v = (n < F_ && k < F_) ? src[(size_t)n * F_ + k] : 0.0f;
        o[j] = f2b(v);
    }
    uint4 w;
    w.x = (unsigned int)o[0] | ((unsigned int)o[1] << 16);
    w.y = (unsigned int)o[2] | ((unsigned int)o[3] << 16);
    w.z = (unsigned int)o[4] | ((unsigned int)o[5] << 16);
    w.w = (unsigned int)o[6] | ((unsigned int)o[7] << 16);
    ((uint4*)WF)[i] = w;
}

// ===== gathered score half only: s2[i] = alW2 · feat[i] =====
#define SN 32
__global__ __launch_bounds__(NT)
void score2_kernel(const float* __restrict__ feat, const float* __restrict__ alW2,
                   float* __restrict__ s2)
{
    const int tid  = threadIdx.x;
    const int node = blockIdx.x * SN + (tid >> 3);
    const int sub  = tid & 7;
    const float* row = feat + (size_t)node * F_;
    float b = 0.0f;
    for (int k = sub; k < F_; k += 8) b += row[k] * alW2[k];
    b += __shfl_xor(b, 1, 8); b += __shfl_xor(b, 2, 8); b += __shfl_xor(b, 4, 8);
    if (sub == 0) s2[node] = b;
}

// ===================== round kernel (MFMA E/F, tile-sequential) =====================
__global__ __launch_bounds__(NT)
void round_kernel(
    const int*   __restrict__ atom_degree,
    const int*   __restrict__ bond_degree,
    const float* __restrict__ align_W,       // [2F] this round
    const float* __restrict__ align_b,       // [1]
    const unsigned short* __restrict__ WF,   // 7 fragment matrices this round
    const float* __restrict__ attend_b,
    const float* __restrict__ gru_bih,
    const float* __restrict__ gru_bhh,
    const float* __restrict__ nbr_b,         // mode0
    const float* __restrict__ PA,            // mode0
    const float* __restrict__ PB,            // mode0
    const float* __restrict__ s2_tab,        // mode1 gathered score half
    const float* __restrict__ cur_in,        // [B,L,F]
    float*       __restrict__ dst,
    int mode)
{
    // XCD swizzle: all 8 tiles of a molecule share (blockIdx % 8) -> same XCD L2
    const int bid   = blockIdx.x;
    const int mol   = ((bid >> 6) << 3) | (bid & 7);
    const int tile  = (bid >> 3) & 7;
    const int node0 = mol * L_ + tile * NTILE;
    const int bL    = mol * L_;
    const int tid   = threadIdx.x;
    const int lane  = tid & 63;
    const int wave  = tid >> 6;

    __shared__ __align__(16) float cur_s[NTILE][F_];             // fp32, final combine
    __shared__ __align__(16) unsigned short curb  [NTILE][KPP];  // bf16 A-operands
    __shared__ __align__(16) unsigned short mixedb[NTILE][KPP];
    __shared__ __align__(16) unsigned short ctxb  [NTILE][KPP];
    __shared__ __align__(16) float alW2_s[F_];
    __shared__ __align__(16) float nbrb_s[F_];
    __shared__ float sc_s [NQ];
    __shared__ float asum_s[NTILE];
    __shared__ float s1_s[NTILE];
    __shared__ int   nidx_s[NQ];
    __shared__ int   bidx_s[NQ];

    // zero K-pads [F_, KP) (MFMA reads them; pad x Wpad = 0 required)
    for (int idx = tid; idx < NTILE * (KP - F_); idx += NT) {
        const int n = idx / (KP - F_), k = F_ + idx % (KP - F_);
        curb[n][k] = 0; mixedb[n][k] = 0; ctxb[n][k] = 0;
    }

    if (tid < NQ) {
        const int n = tid / D_, j = tid - n * D_;
        nidx_s[tid] = atom_degree[(node0 + n) * D_ + j] & LMASK;
        bidx_s[tid] = (mode == 0) ? (bond_degree[(node0 + n) * D_ + j] & LMASK) : 0;
    }
    if (mode == 0 && tid < F_) {
        alW2_s[tid] = align_W[F_ + tid];
        nbrb_s[tid] = nbr_b[tid];
    }

    // Phase A: own cur rows (fp32 + bf16)
    for (int idx = tid; idx < NTILE * KC; idx += NT) {
        const int n = idx / KC, kk = idx - n * KC;
        const float4 v = ((const float4*)(cur_in + (size_t)(node0 + n) * F_))[kk];
        ((float4*)cur_s[n])[kk] = v;
        *(uint2*)&curb[n][kk * 4] = pack4(v);
    }
    __syncthreads();

    // inline s1[n] = alW1 · cur[n] (16 lanes per node)
    {
        const int n = tid >> 4, sub = tid & 15;
        float a = 0.0f;
        for (int f = sub; f < F_; f += 16) a += cur_s[n][f] * align_W[f];
        a += __shfl_xor(a, 1, 16); a += __shfl_xor(a, 2, 16);
        a += __shfl_xor(a, 4, 16); a += __shfl_xor(a, 8, 16);
        if (sub == 0) s1_s[n] = a;
    }
    __syncthreads();

    // Phase C: align scores
    if (mode == 0) {
        if (tid < NQ * 2) {      // 2 lanes per pair, float4
            const int q = tid >> 1, sub = tid & 1;
            const int n = q / D_;
            const float4* pa4 = (const float4*)(PA + (size_t)(bL + nidx_s[q]) * F_);
            const float4* pb4 = (const float4*)(PB + (size_t)(bL + bidx_s[q]) * F_);
            float s = 0.0f;
            for (int kk = sub; kk < KC; kk += 2) {
                const float4 pa = pa4[kk], pb = pb4[kk];
                const float4 w  = ((const float4*)alW2_s)[kk];
                const float4 bb = ((const float4*)nbrb_s)[kk];
                s += lrelu(pa.x + pb.x + bb.x) * w.x + lrelu(pa.y + pb.y + bb.y) * w.y
                   + lrelu(pa.z + pb.z + bb.z) * w.z + lrelu(pa.w + pb.w + bb.w) * w.w;
            }
            s += __shfl_xor(s, 1, 2);
            if (sub == 0) {
                float sc = lrelu(s + s1_s[n] + align_b[0]);
                if (nidx_s[q] == PAD_) sc += -9.0e8f;
                sc_s[q] = sc;
            }
        }
    } else {
        if (tid < NQ) {
            const int n = tid / D_;
            float sc = lrelu(s1_s[n] + s2_tab[bL + nidx_s[tid]] + align_b[0]);
            if (nidx_s[tid] == PAD_) sc += -9.0e8f;
            sc_s[tid] = sc;
        }
    }
    __syncthreads();

    // masked softmax over D per node
    if (tid < NTILE) {
        float m = sc_s[tid * D_];
        #pragma unroll
        for (int j = 1; j < D_; ++j) m = fmaxf(m, sc_s[tid * D_ + j]);
        float ex[D_]; float ssum = 0.0f;
        #pragma unroll
        for (int j = 0; j < D_; ++j) { ex[j] = __expf(sc_s[tid * D_ + j] - m); ssum += ex[j]; }
        const float inv = 1.0f / ssum;
        float as = 0.0f;
        #pragma unroll
        for (int j = 0; j < D_; ++j) {
            const float a = (nidx_s[tid * D_ + j] == PAD_) ? 0.0f : ex[j] * inv;
            sc_s[tid * D_ + j] = a;
            as += a;
        }
        asum_s[tid] = as;
    }
    __syncthreads();

    // Phase D: mixed[n] = sum_j attn_j * nbr_feat_j -> bf16 LDS
    for (int idx = tid; idx < NTILE * KC; idx += NT) {
        const int n = idx / KC, kk = idx - n * KC;
        float4 m4 = make_float4(0.f, 0.f, 0.f, 0.f);
        if (mode == 0) {
            const float4 bb4 = ((const float4*)nbrb_s)[kk];
            #pragma unroll
            for (int j = 0; j < D_; ++j) {
                const float a = sc_s[n * D_ + j];
                const float4 pa4 = ((const float4*)(PA + (size_t)(bL + nidx_s[n*D_+j]) * F_))[kk];
                const float4 pb4 = ((const float4*)(PB + (size_t)(bL + bidx_s[n*D_+j]) * F_))[kk];
                m4.x += a * lrelu(pa4.x + pb4.x + bb4.x);
                m4.y += a * lrelu(pa4.y + pb4.y + bb4.y);
                m4.z += a * lrelu(pa4.z + pb4.z + bb4.z);
                m4.w += a * lrelu(pa4.w + pb4.w + bb4.w);
            }
        } else {
            #pragma unroll
            for (int j = 0; j < D_; ++j) {
                const float a = sc_s[n * D_ + j];
                const float4 v = ((const float4*)(cur_in + (size_t)(bL + nidx_s[n*D_+j]) * F_))[kk];
                m4.x += a * v.x; m4.y += a * v.y; m4.z += a * v.z; m4.w += a * v.w;
            }
        }
        *(uint2*)&mixedb[n][kk * 4] = pack4(m4);
    }
    __syncthreads();

    // ---- Phase E (MFMA, tile-sequential): ctx = elu(attend_W @ mixed + asum*b) ----
    for (int t = wave; t < NTL; t += 4) {
        f32x4 acc = {0.f, 0.f, 0.f, 0.f};
        #pragma unroll
        for (int ks = 0; ks < KSTEPS; ++ks)
            acc = __builtin_amdgcn_mfma_f32_16x16x32_bf16(
                AFRAG(mixedb, ks), bfrag(WF, 0, t, ks, lane), acc, 0, 0, 0);
        const int f = t * 16 + (lane & 15);
        if (f < F_) {
            const float bb = attend_b[f];
            #pragma unroll
            for (int rg = 0; rg < 4; ++rg) {
                const int node = ((lane >> 4) << 2) + rg;
                float c = acc[rg] + asum_s[node] * bb;
                c = (c > 0.0f) ? c : (__expf(c) - 1.0f);
                ctxb[node][f] = f2b(c);
            }
        }
    }
    __syncthreads();

    // ---- Phase F (MFMA, tile-sequential): GRU gates ----
    for (int t = wave; t < NTL; t += 4) {
        f32x4 ar = {0.f,0.f,0.f,0.f}, az = {0.f,0.f,0.f,0.f};
        f32x4 ani = {0.f,0.f,0.f,0.f}, anh = {0.f,0.f,0.f,0.f};
        #pragma unroll
        for (int ks = 0; ks < KSTEPS; ++ks) {
            const sh8 ac = AFRAG(ctxb, ks);
            const sh8 ah = AFRAG(curb, ks);
            ar  = __builtin_amdgcn_mfma_f32_16x16x32_bf16(ac, bfrag(WF,1,t,ks,lane), ar, 0,0,0);
            ar  = __builtin_amdgcn_mfma_f32_16x16x32_bf16(ah, bfrag(WF,4,t,ks,lane), ar, 0,0,0);
            az  = __builtin_amdgcn_mfma_f32_16x16x32_bf16(ac, bfrag(WF,2,t,ks,lane), az, 0,0,0);
            az  = __builtin_amdgcn_mfma_f32_16x16x32_bf16(ah, bfrag(WF,5,t,ks,lane), az, 0,0,0);
            ani = __builtin_amdgcn_mfma_f32_16x16x32_bf16(ac, bfrag(WF,3,t,ks,lane), ani, 0,0,0);
            anh = __builtin_amdgcn_mfma_f32_16x16x32_bf16(ah, bfrag(WF,6,t,ks,lane), anh, 0,0,0);
        }
        const int f = t * 16 + (lane & 15);
        if (f < F_) {
            const float bir = gru_bih[f],        bhr = gru_bhh[f];
            const float biz = gru_bih[F_ + f],   bhz = gru_bhh[F_ + f];
            const float bin = gru_bih[2*F_ + f], bhn = gru_bhh[2*F_ + f];
            #pragma unroll
            for (int rg = 0; rg < 4; ++rg) {
                const int node = ((lane >> 4) << 2) + rg;
                const float r  = sigm(ar[rg] + bir + bhr);
                const float z  = sigm(az[rg] + biz + bhz);
                const float nn = tanhf(ani[rg] + bin + r * (anh[rg] + bhn));
                const float h  = (1.0f - z) * nn + z * cur_s[node][f];
                dst[(size_t)(node0 + node) * F_ + f] = fmaxf(h, 0.0f);
            }
        }
    }
}

extern "C" __attribute__((visibility("default")))
void kernel_launch(void* const* d_in, const int* in_sizes, int n_in,
                   void* d_out, int out_size, void* d_ws, size_t ws_size,
                   hipStream_t stream) {
    const float* atom_list = (const float*)d_in[0];
    const float* bond_list = (const float*)d_in[1];
    const int*   atom_deg  = (const int*)d_in[2];
    const int*   bond_deg  = (const int*)d_in[3];
    const float* atom_W    = (const float*)d_in[4];
    const float* atom_b    = (const float*)d_in[5];
    const float* nbr_W     = (const float*)d_in[6];
    const float* nbr_b     = (const float*)d_in[7];
    const float* align_W   = (const float*)d_in[8];
    const float* align_b   = (const float*)d_in[9];
    const float* attend_W  = (const float*)d_in[10];
    const float* attend_b  = (const float*)d_in[11];
    const float* gru_Wih   = (const float*)d_in[12];
    const float* gru_Whh   = (const float*)d_in[13];
    const float* gru_bih   = (const float*)d_in[14];
    const float* gru_bhh   = (const float*)d_in[15];

    float* ws   = (float*)d_ws;
    float* cur0 = ws;
    float* PA   = ws + (size_t)NF;
    float* PB   = ws + (size_t)2*NF;
    float* cur1 = ws + (size_t)3*NF;
    float* s2b  = ws + (size_t)4*NF;
    unsigned short* WF = (unsigned short*)(s2b + NNODES);   // 1.3 MB bf16 fragments
    float* out  = (float*)d_out;

    prep_kernel<<<dim3(NNODES / PN2), dim3(NT), 0, stream>>>(
        atom_list, bond_list, atom_W, atom_b, nbr_W, cur0, PA, PB);

    build_frags<<<dim3((FRAG_TOTAL + NT - 1) / NT), dim3(NT), 0, stream>>>(
        attend_W, gru_Wih, gru_Whh, WF);

    const dim3 grid(NNODES / NTILE);
    const size_t rframe = (size_t)7 * NTL * KSTEPS * 64 * 8;  // shorts per round

    round_kernel<<<grid, dim3(NT), 0, stream>>>(
        atom_deg, bond_deg, align_W, align_b,
        WF, attend_b, gru_bih, gru_bhh,
        nbr_b, PA, PB, /*s2_tab*/nullptr, cur0, cur1, 0);

    score2_kernel<<<dim3(NNODES / SN), dim3(NT), 0, stream>>>(
        cur1, align_W + 2 * F_ + F_, s2b);

    round_kernel<<<grid, dim3(NT), 0, stream>>>(
        atom_deg, bond_deg, align_W + 2 * F_, align_b + 1,
        WF + rframe, attend_b + F_, gru_bih + 3 * F_, gru_bhh + 3 * F_,
        nbr_b, PA, PB, s2b, cur1, out, 1);
}

// Round 3
// 383.618 us; speedup vs baseline: 1.9241x; 1.1017x over previous
//
#include <hip/hip_runtime.h>

#define B_     256
#define L_     128
#define D_     6
#define F_     200
#define FA_    39
#define FB_    10
#define PAD_   127       // L-1 padding atom index
#define LMASK  127
#define NT     256
#define KC     (F_/4)    // 50 float4 chunks per F-row
#define NTILE  16
#define NQ     (NTILE * D_)   // 96 pairs
#define NF     (B_ * L_ * F_) // 6,553,600 floats
#define MSZ    (F_ * F_)      // 40,000 floats per matrix
#define NNODES (B_ * L_)      // 32768
#define NPAIRS (NNODES * D_)  // 196608
#define KP     224            // K padded to 7*32 (MFMA reads k < 224)
#define KPP    232            // LDS row stride: 464B -> bank step 20 (conflict-free)
#define KSTEPS 7
#define NTL    13             // N tiles of 16 (200 -> 208)
#define FRAG_TOTAL (14 * NTL * KSTEPS * 64)

typedef __attribute__((ext_vector_type(8))) short sh8;
typedef __attribute__((ext_vector_type(4))) float f32x4;

__device__ __forceinline__ float lrelu(float x) { return x >= 0.0f ? x : 0.01f * x; }
__device__ __forceinline__ float sigm(float x)  { return 1.0f / (1.0f + __expf(-x)); }
__device__ __forceinline__ unsigned short f2b(float x) {   // fp32 -> bf16 RNE
    unsigned int u = __float_as_uint(x);
    unsigned int r = (u + 0x7FFFu + ((u >> 16) & 1u)) >> 16;
    return (unsigned short)r;
}
__device__ __forceinline__ uint2 pack4(float4 v) {
    uint2 p;
    p.x = (unsigned int)f2b(v.x) | ((unsigned int)f2b(v.y) << 16);
    p.y = (unsigned int)f2b(v.z) | ((unsigned int)f2b(v.w) << 16);
    return p;
}
// A-fragment from LDS bf16 [NTILE][KPP]: A[m=lane&15][k=ks*32+quad*8+j]
#define AFRAG(arr, ks) (*(const sh8*)&arr[lane & 15][(ks) * 32 + ((lane >> 4) << 3)])
__device__ __forceinline__ sh8 bfrag(const unsigned short* __restrict__ WFr,
                                     int mat, int t, int ks, int lane) {
    return *(const sh8*)(WFr + ((((size_t)mat * NTL + t) * KSTEPS + ks) * 64 + lane) * 8);
}

// ============== prep: cur0 = lrelu(atom emb), PA/PB partial nbr emb ==============
// Weight-stationary: lane owns output column f, weights in registers; node
// inputs are wave-uniform scalar loads; stores coalesced. (405us -> fixed)
#define PN2 64
__global__ __launch_bounds__(NT)
void prep_kernel(const float* __restrict__ atom_list, const float* __restrict__ bond_list,
                 const float* __restrict__ atom_W, const float* __restrict__ atom_b,
                 const float* __restrict__ nbr_W,
                 float* __restrict__ cur0, float* __restrict__ PA, float* __restrict__ PB)
{
    const int node0 = blockIdx.x * PN2;
    const int tid   = threadIdx.x;
    const int f     = tid;
    const bool valid = (f < F_);
    const int fc    = valid ? f : 0;

    __shared__ float wsh[F_ * (FA_ + FB_)];   // 9800 floats = 39.2 KB

    float wa[FA_];
    float wn[FA_ + FB_];

    for (int i = tid; i < F_ * FA_; i += NT) wsh[i] = atom_W[i];
    __syncthreads();
    #pragma unroll
    for (int k = 0; k < FA_; ++k) wa[k] = wsh[fc * FA_ + k];
    __syncthreads();
    for (int i = tid; i < F_ * (FA_ + FB_); i += NT) wsh[i] = nbr_W[i];
    __syncthreads();
    #pragma unroll
    for (int k = 0; k < FA_ + FB_; ++k) wn[k] = wsh[fc * (FA_ + FB_) + k];

    const float ab = atom_b[fc];

    for (int n = 0; n < PN2; ++n) {
        const float* __restrict__ ar = atom_list + (size_t)(node0 + n) * FA_;
        const float* __restrict__ br = bond_list + (size_t)(node0 + n) * FB_;
        float accA = ab, accPA = 0.0f, accPB = 0.0f;
        #pragma unroll
        for (int k = 0; k < FA_; ++k) {
            const float a = ar[k];          // wave-uniform -> scalar load
            accA  += a * wa[k];
            accPA += a * wn[k];
        }
        #pragma unroll
        for (int k = 0; k < FB_; ++k) accPB += br[k] * wn[FA_ + k];
        if (valid) {
            const size_t o = (size_t)(node0 + n) * F_ + f;
            cur0[o] = lrelu(accA);
            PA[o]   = accPA;
            PB[o]   = accPB;
        }
    }
}

// ===== build bf16 B-fragments for 14 F×F matrices (zero-padded to 208×224) =====
__global__ void build_frags(const float* __restrict__ attend_W,
                            const float* __restrict__ gru_Wih,
                            const float* __restrict__ gru_Whh,
                            unsigned short* __restrict__ WF)
{
    const int i = blockIdx.x * blockDim.x + threadIdx.x;
    if (i >= FRAG_TOTAL) return;
    const int lane = i & 63;
    int rest = i >> 6;
    const int ks = rest % KSTEPS; rest /= KSTEPS;
    const int t  = rest % NTL;
    const int m  = rest / NTL;
    const int n  = t * 16 + (lane & 15);
    const int k0 = ks * 32 + ((lane >> 4) << 3);
    const int r = m / 7, tt = m - r * 7;
    const float* src;
    if (tt == 0)      src = attend_W + (size_t)r * MSZ;
    else if (tt <= 3) src = gru_Wih + ((size_t)r * 3 + (tt - 1)) * MSZ;
    else              src = gru_Whh + ((size_t)r * 3 + (tt - 4)) * MSZ;
    unsigned short o[8];
    #pragma unroll
    for (int j = 0; j < 8; ++j) {
        const int k = k0 + j;
        const float v = (n < F_ && k < F_) ? src[(size_t)n * F_ + k] : 0.0f;
        o[j] = f2b(v);
    }
    uint4 w;
    w.x = (unsigned int)o[0] | ((unsigned int)o[1] << 16);
    w.y = (unsigned int)o[2] | ((unsigned int)o[3] << 16);
    w.z = (unsigned int)o[4] | ((unsigned int)o[5] << 16);
    w.w = (unsigned int)o[6] | ((unsigned int)o[7] << 16);
    ((uint4*)WF)[i] = w;
}

// ===== gathered score half only: s2[i] = alW2 · feat[i]  (mode-1 table) =====
#define SN 32
__global__ __launch_bounds__(NT)
void score2_kernel(const float* __restrict__ feat, const float* __restrict__ alW2,
                   float* __restrict__ s2)
{
    const int tid  = threadIdx.x;
    const int node = blockIdx.x * SN + (tid >> 3);
    const int sub  = tid & 7;
    const float* row = feat + (size_t)node * F_;
    float b = 0.0f;
    for (int k = sub; k < F_; k += 8) b += row[k] * alW2[k];
    b += __shfl_xor(b, 1, 8); b += __shfl_xor(b, 2, 8); b += __shfl_xor(b, 4, 8);
    if (sub == 0) s2[node] = b;
}

// ===== mode-0 pair-score table: s2p[q] = alW2 · lrelu(PA[nidx]+PB[bidx]+nbr_b) =====
// High-occupancy (tiny LDS, no barriers in hot loop): the gather latency that
// previously sat inside round_kernel's barrier-synced Phase C is hidden by TLP.
#define PPB 32   // pairs per block, 8 lanes each
__global__ __launch_bounds__(NT)
void pair_score_kernel(const int* __restrict__ atom_degree,
                       const int* __restrict__ bond_degree,
                       const float* __restrict__ PA, const float* __restrict__ PB,
                       const float* __restrict__ alW2, const float* __restrict__ nbr_b,
                       float* __restrict__ s2p)
{
    __shared__ float w_s[F_], b_s[F_];
    const int tid = threadIdx.x;
    if (tid < F_) { w_s[tid] = alW2[tid]; b_s[tid] = nbr_b[tid]; }
    // XCD-aligned swizzle: molecule m -> XCD m%8 (matches round_kernel)
    const int xcd = blockIdx.x & 7;
    const int j   = blockIdx.x >> 3;            // 0..767
    const int mol = (j / 24) * 8 + xcd;         // 24 blocks per molecule
    const int q0  = mol * (L_ * D_) + (j % 24) * PPB;
    const int q   = q0 + (tid >> 3);
    const int sub = tid & 7;
    const int nidx = atom_degree[q] & LMASK;
    const int bidx = bond_degree[q] & LMASK;
    const int bL   = mol * L_;
    const float4* pa4 = (const float4*)(PA + (size_t)(bL + nidx) * F_);
    const float4* pb4 = (const float4*)(PB + (size_t)(bL + bidx) * F_);
    __syncthreads();
    float s = 0.0f;
    for (int kk = sub; kk < KC; kk += 8) {
        const float4 pa = pa4[kk], pb = pb4[kk];
        const float4 w  = ((const float4*)w_s)[kk];
        const float4 bb = ((const float4*)b_s)[kk];
        s += lrelu(pa.x + pb.x + bb.x) * w.x + lrelu(pa.y + pb.y + bb.y) * w.y
           + lrelu(pa.z + pb.z + bb.z) * w.z + lrelu(pa.w + pb.w + bb.w) * w.w;
    }
    s += __shfl_xor(s, 1, 8); s += __shfl_xor(s, 2, 8); s += __shfl_xor(s, 4, 8);
    if (sub == 0) s2p[q] = s;
}

// ===================== round kernel (MFMA E/F, tile-sequential) =====================
// launch_bounds(256,4): 128-VGPR budget so the compiler can keep Phase-D's 12
// gathers and Phase-E/F's bfrag streams in flight (was 60 VGPRs -> stall city).
// LDS 24.4KB (cur_s dropped; Phase F / s1 read cur_in directly, bit-identical).
__global__ __launch_bounds__(NT, 4)
void round_kernel(
    const int*   __restrict__ atom_degree,
    const int*   __restrict__ bond_degree,
    const float* __restrict__ align_W,       // [2F] this round (first half used)
    const float* __restrict__ align_b,       // [1]
    const unsigned short* __restrict__ WF,   // 7 fragment matrices this round
    const float* __restrict__ attend_b,
    const float* __restrict__ gru_bih,
    const float* __restrict__ gru_bhh,
    const float* __restrict__ nbr_b,         // mode0
    const float* __restrict__ PA,            // mode0
    const float* __restrict__ PB,            // mode0
    const float* __restrict__ s2_tab,        // mode0: per-pair table; mode1: per-node
    const float* __restrict__ cur_in,        // [B,L,F]
    float*       __restrict__ dst,
    int mode)
{
    // XCD swizzle: all 8 tiles of a molecule share (blockIdx % 8) -> same XCD L2
    const int bid   = blockIdx.x;
    const int mol   = ((bid >> 6) << 3) | (bid & 7);
    const int tile  = (bid >> 3) & 7;
    const int node0 = mol * L_ + tile * NTILE;
    const int bL    = mol * L_;
    const int tid   = threadIdx.x;
    const int lane  = tid & 63;
    const int wave  = tid >> 6;

    __shared__ __align__(16) unsigned short curb  [NTILE][KPP];  // bf16 A-operands
    __shared__ __align__(16) unsigned short mixedb[NTILE][KPP];
    __shared__ __align__(16) unsigned short ctxb  [NTILE][KPP];
    __shared__ __align__(16) float nbrb_s[F_];
    __shared__ float sc_s [NQ];
    __shared__ float asum_s[NTILE];
    __shared__ float s1_s[NTILE];
    __shared__ int   nidx_s[NQ];
    __shared__ int   bidx_s[NQ];

    // zero K-pads [F_, KP) (MFMA reads them; pad x Wpad = 0 required)
    for (int idx = tid; idx < NTILE * (KP - F_); idx += NT) {
        const int n = idx / (KP - F_), k = F_ + idx % (KP - F_);
        curb[n][k] = 0; mixedb[n][k] = 0; ctxb[n][k] = 0;
    }

    if (tid < NQ) {
        const int n = tid / D_, j = tid - n * D_;
        nidx_s[tid] = atom_degree[(node0 + n) * D_ + j] & LMASK;
        bidx_s[tid] = (mode == 0) ? (bond_degree[(node0 + n) * D_ + j] & LMASK) : 0;
    }
    if (mode == 0 && tid < F_) nbrb_s[tid] = nbr_b[tid];

    // Phase A: own cur rows -> bf16 LDS
    for (int idx = tid; idx < NTILE * KC; idx += NT) {
        const int n = idx / KC, kk = idx - n * KC;
        const float4 v = ((const float4*)(cur_in + (size_t)(node0 + n) * F_))[kk];
        *(uint2*)&curb[n][kk * 4] = pack4(v);
    }

    // s1[n] = alW1 · cur[n] (16 lanes per node, direct from global — no LDS dep)
    {
        const int n = tid >> 4, sub = tid & 15;
        const float* crow = cur_in + (size_t)(node0 + n) * F_;
        float a = 0.0f;
        for (int f = sub; f < F_; f += 16) a += crow[f] * align_W[f];
        a += __shfl_xor(a, 1, 16); a += __shfl_xor(a, 2, 16);
        a += __shfl_xor(a, 4, 16); a += __shfl_xor(a, 8, 16);
        if (sub == 0) s1_s[n] = a;
    }
    __syncthreads();

    // Phase C: align scores — table lookup in BOTH modes now
    if (tid < NQ) {
        const int n = tid / D_;
        const float s2v = (mode == 0)
            ? s2_tab[(size_t)(node0 + n) * D_ + (tid - n * D_)]
            : s2_tab[bL + nidx_s[tid]];
        float sc = lrelu(s1_s[n] + s2v + align_b[0]);
        if (nidx_s[tid] == PAD_) sc += -9.0e8f;
        sc_s[tid] = sc;
    }
    __syncthreads();

    // masked softmax over D per node
    if (tid < NTILE) {
        float m = sc_s[tid * D_];
        #pragma unroll
        for (int j = 1; j < D_; ++j) m = fmaxf(m, sc_s[tid * D_ + j]);
        float ex[D_]; float ssum = 0.0f;
        #pragma unroll
        for (int j = 0; j < D_; ++j) { ex[j] = __expf(sc_s[tid * D_ + j] - m); ssum += ex[j]; }
        const float inv = 1.0f / ssum;
        float as = 0.0f;
        #pragma unroll
        for (int j = 0; j < D_; ++j) {
            const float a = (nidx_s[tid * D_ + j] == PAD_) ? 0.0f : ex[j] * inv;
            sc_s[tid * D_ + j] = a;
            as += a;
        }
        asum_s[tid] = as;
    }
    __syncthreads();

    // Phase D: mixed[n] = sum_j attn_j * nbr_feat_j -> bf16 LDS
    for (int idx = tid; idx < NTILE * KC; idx += NT) {
        const int n = idx / KC, kk = idx - n * KC;
        float4 m4 = make_float4(0.f, 0.f, 0.f, 0.f);
        if (mode == 0) {
            const float4 bb4 = ((const float4*)nbrb_s)[kk];
            #pragma unroll
            for (int j = 0; j < D_; ++j) {
                const float a = sc_s[n * D_ + j];
                const float4 pa4 = ((const float4*)(PA + (size_t)(bL + nidx_s[n*D_+j]) * F_))[kk];
                const float4 pb4 = ((const float4*)(PB + (size_t)(bL + bidx_s[n*D_+j]) * F_))[kk];
                m4.x += a * lrelu(pa4.x + pb4.x + bb4.x);
                m4.y += a * lrelu(pa4.y + pb4.y + bb4.y);
                m4.z += a * lrelu(pa4.z + pb4.z + bb4.z);
                m4.w += a * lrelu(pa4.w + pb4.w + bb4.w);
            }
        } else {
            #pragma unroll
            for (int j = 0; j < D_; ++j) {
                const float a = sc_s[n * D_ + j];
                const float4 v = ((const float4*)(cur_in + (size_t)(bL + nidx_s[n*D_+j]) * F_))[kk];
                m4.x += a * v.x; m4.y += a * v.y; m4.z += a * v.z; m4.w += a * v.w;
            }
        }
        *(uint2*)&mixedb[n][kk * 4] = pack4(m4);
    }
    __syncthreads();

    // ---- Phase E (MFMA, tile-sequential): ctx = elu(attend_W @ mixed + asum*b) ----
    for (int t = wave; t < NTL; t += 4) {
        f32x4 acc = {0.f, 0.f, 0.f, 0.f};
        #pragma unroll
        for (int ks = 0; ks < KSTEPS; ++ks)
            acc = __builtin_amdgcn_mfma_f32_16x16x32_bf16(
                AFRAG(mixedb, ks), bfrag(WF, 0, t, ks, lane), acc, 0, 0, 0);
        const int f = t * 16 + (lane & 15);
        if (f < F_) {
            const float bb = attend_b[f];
            #pragma unroll
            for (int rg = 0; rg < 4; ++rg) {
                const int node = ((lane >> 4) << 2) + rg;
                float c = acc[rg] + asum_s[node] * bb;
                c = (c > 0.0f) ? c : (__expf(c) - 1.0f);
                ctxb[node][f] = f2b(c);
            }
        }
    }
    __syncthreads();

    // ---- Phase F (MFMA, tile-sequential): GRU gates ----
    for (int t = wave; t < NTL; t += 4) {
        f32x4 ar = {0.f,0.f,0.f,0.f}, az = {0.f,0.f,0.f,0.f};
        f32x4 ani = {0.f,0.f,0.f,0.f}, anh = {0.f,0.f,0.f,0.f};
        #pragma unroll
        for (int ks = 0; ks < KSTEPS; ++ks) {
            const sh8 ac = AFRAG(ctxb, ks);
            const sh8 ah = AFRAG(curb, ks);
            ar  = __builtin_amdgcn_mfma_f32_16x16x32_bf16(ac, bfrag(WF,1,t,ks,lane), ar, 0,0,0);
            ar  = __builtin_amdgcn_mfma_f32_16x16x32_bf16(ah, bfrag(WF,4,t,ks,lane), ar, 0,0,0);
            az  = __builtin_amdgcn_mfma_f32_16x16x32_bf16(ac, bfrag(WF,2,t,ks,lane), az, 0,0,0);
            az  = __builtin_amdgcn_mfma_f32_16x16x32_bf16(ah, bfrag(WF,5,t,ks,lane), az, 0,0,0);
            ani = __builtin_amdgcn_mfma_f32_16x16x32_bf16(ac, bfrag(WF,3,t,ks,lane), ani, 0,0,0);
            anh = __builtin_amdgcn_mfma_f32_16x16x32_bf16(ah, bfrag(WF,6,t,ks,lane), anh, 0,0,0);
        }
        const int f = t * 16 + (lane & 15);
        if (f < F_) {
            const float bir = gru_bih[f],        bhr = gru_bhh[f];
            const float biz = gru_bih[F_ + f],   bhz = gru_bhh[F_ + f];
            const float bin = gru_bih[2*F_ + f], bhn = gru_bhh[2*F_ + f];
            #pragma unroll
            for (int rg = 0; rg < 4; ++rg) {
                const int node = ((lane >> 4) << 2) + rg;
                const float r  = sigm(ar[rg] + bir + bhr);
                const float z  = sigm(az[rg] + biz + bhz);
                const float nn = tanhf(ani[rg] + bin + r * (anh[rg] + bhn));
                const float cv = cur_in[(size_t)(node0 + node) * F_ + f];
                const float h  = (1.0f - z) * nn + z * cv;
                dst[(size_t)(node0 + node) * F_ + f] = fmaxf(h, 0.0f);
            }
        }
    }
}

extern "C" __attribute__((visibility("default")))
void kernel_launch(void* const* d_in, const int* in_sizes, int n_in,
                   void* d_out, int out_size, void* d_ws, size_t ws_size,
                   hipStream_t stream) {
    const float* atom_list = (const float*)d_in[0];
    const float* bond_list = (const float*)d_in[1];
    const int*   atom_deg  = (const int*)d_in[2];
    const int*   bond_deg  = (const int*)d_in[3];
    const float* atom_W    = (const float*)d_in[4];
    const float* atom_b    = (const float*)d_in[5];
    const float* nbr_W     = (const float*)d_in[6];
    const float* nbr_b     = (const float*)d_in[7];
    const float* align_W   = (const float*)d_in[8];
    const float* align_b   = (const float*)d_in[9];
    const float* attend_W  = (const float*)d_in[10];
    const float* attend_b  = (const float*)d_in[11];
    const float* gru_Wih   = (const float*)d_in[12];
    const float* gru_Whh   = (const float*)d_in[13];
    const float* gru_bih   = (const float*)d_in[14];
    const float* gru_bhh   = (const float*)d_in[15];

    float* ws   = (float*)d_ws;
    float* cur0 = ws;
    float* PA   = ws + (size_t)NF;
    float* PB   = ws + (size_t)2*NF;
    float* cur1 = ws + (size_t)3*NF;
    float* s2b  = ws + (size_t)4*NF;
    unsigned short* WF = (unsigned short*)(s2b + NNODES);   // 1.3 MB bf16 fragments
    float* s2p  = (float*)(WF + (size_t)FRAG_TOTAL * 8);    // mode-0 pair-score table
    float* out  = (float*)d_out;

    prep_kernel<<<dim3(NNODES / PN2), dim3(NT), 0, stream>>>(
        atom_list, bond_list, atom_W, atom_b, nbr_W, cur0, PA, PB);

    build_frags<<<dim3((FRAG_TOTAL + NT - 1) / NT), dim3(NT), 0, stream>>>(
        attend_W, gru_Wih, gru_Whh, WF);

    pair_score_kernel<<<dim3(NPAIRS / PPB), dim3(NT), 0, stream>>>(
        atom_deg, bond_deg, PA, PB, align_W + F_, nbr_b, s2p);

    const dim3 grid(NNODES / NTILE);
    const size_t rframe = (size_t)7 * NTL * KSTEPS * 64 * 8;  // shorts per round

    round_kernel<<<grid, dim3(NT), 0, stream>>>(
        atom_deg, bond_deg, align_W, align_b,
        WF, attend_b, gru_bih, gru_bhh,
        nbr_b, PA, PB, /*s2_tab*/s2p, cur0, cur1, 0);

    score2_kernel<<<dim3(NNODES / SN), dim3(NT), 0, stream>>>(
        cur1, align_W + 2 * F_ + F_, s2b);

    round_kernel<<<grid, dim3(NT), 0, stream>>>(
        atom_deg, bond_deg, align_W + 2 * F_, align_b + 1,
        WF + rframe, attend_b + F_, gru_bih + 3 * F_, gru_bhh + 3 * F_,
        nbr_b, PA, PB, s2b, cur1, out, 1);
}